// Round 1
// baseline (499.718 us; speedup 1.0000x reference)
//
#include <hip/hip_runtime.h>
#include <hip/hip_bf16.h>

typedef __attribute__((ext_vector_type(4))) float f32x4;
typedef __attribute__((ext_vector_type(8))) short short8;
typedef unsigned short u16;

__device__ inline float bf2f(u16 u) {
    unsigned int x = ((unsigned int)u) << 16;
    return __builtin_bit_cast(float, x);
}
__device__ inline u16 f2bf(float f) {
    unsigned int x = __builtin_bit_cast(unsigned int, f);
    unsigned int r = (x + 0x7FFFu + ((x >> 16) & 1u)) >> 16;
    return (u16)r;
}

__device__ inline int edge_at(const void* edges, int flag64, long long idx) {
    if (flag64) return (int)((const long long*)edges)[idx];
    return ((const int*)edges)[idx];
}

// ---------------- probe: int64 vs int32 edge_index ----------------
__global__ void probe_kernel(const void* edges, int n, int* flag) {
    if (threadIdx.x == 0 && blockIdx.x == 0) {
        const long long* p = (const long long*)edges;
        int ok = 1;
        for (int i = 0; i < 64; ++i) {
            long long v = p[i];
            if (v < 0 || v >= n) { ok = 0; break; }
        }
        *flag = ok;
    }
}

// ---------------- CSR build ----------------
__global__ void hist_kernel(const void* edges, const int* flag, int E, int* deg) {
    int f = *flag;
    for (long long i = blockIdx.x * blockDim.x + threadIdx.x; i < E;
         i += (long long)gridDim.x * blockDim.x) {
        int dst = edge_at(edges, f, (long long)E + i);
        atomicAdd(&deg[dst], 1);
    }
}

__global__ void scan1_kernel(const int* deg, int* incl, int* bsum, int n) {
    __shared__ int s[256];
    int i = blockIdx.x * 256 + threadIdx.x;
    int v = (i < n) ? deg[i] : 0;
    s[threadIdx.x] = v;
    __syncthreads();
    for (int d = 1; d < 256; d <<= 1) {
        int t = (threadIdx.x >= d) ? s[threadIdx.x - d] : 0;
        __syncthreads();
        s[threadIdx.x] += t;
        __syncthreads();
    }
    if (i < n) incl[i] = s[threadIdx.x];
    if (threadIdx.x == 255) bsum[blockIdx.x] = s[255];
}

__global__ void scan2_kernel(const int* bsum, int* boff, int nb) {
    __shared__ int s[512];
    int t = threadIdx.x;
    int v = (t < nb) ? bsum[t] : 0;
    s[t] = v;
    __syncthreads();
    for (int d = 1; d < 512; d <<= 1) {
        int u = (t >= d) ? s[t - d] : 0;
        __syncthreads();
        s[t] += u;
        __syncthreads();
    }
    boff[t] = s[t] - v;  // exclusive
}

__global__ void scan3_kernel(const int* incl, const int* deg, const int* boff,
                             int* offs, int* cursor, int n, int E) {
    int i = blockIdx.x * 256 + threadIdx.x;
    if (i < n) {
        int o = boff[blockIdx.x] + incl[i] - deg[i];
        offs[i] = o;
        cursor[i] = o;
    }
    if (i == 0) offs[n] = E;
}

__global__ void scatter_kernel(const void* edges, const int* flag, int E,
                               int* cursor, int* nbr) {
    int f = *flag;
    for (long long i = blockIdx.x * blockDim.x + threadIdx.x; i < E;
         i += (long long)gridDim.x * blockDim.x) {
        int src = edge_at(edges, f, i);
        int dst = edge_at(edges, f, (long long)E + i);
        int pos = atomicAdd(&cursor[dst], 1);
        nbr[pos] = src;
    }
}

// ---------------- conversions ----------------
__global__ void cvt_x_kernel(const float* __restrict__ x, u16* __restrict__ out, long long n4) {
    long long i = blockIdx.x * blockDim.x + threadIdx.x;
    if (i >= n4) return;
    float4 v = ((const float4*)x)[i];
    ushort4 o;
    o.x = f2bf(v.x); o.y = f2bf(v.y); o.z = f2bf(v.z); o.w = f2bf(v.w);
    ((ushort4*)out)[i] = o;
}

// Wt[m*K + k] = bf16(W[k*M + m])
__global__ void cvt_w_kernel(const float* __restrict__ W, u16* __restrict__ Wt, int K, int M) {
    int i = blockIdx.x * blockDim.x + threadIdx.x;
    if (i >= K * M) return;
    int m = i / K, k = i % K;
    Wt[i] = f2bf(W[(size_t)k * M + m]);
}

// ---------------- aggregation: h = x + sum_{nbr} x[nbr] ----------------
template <int FP>  // features per lane (2 for d=128, 4 for d=256)
__global__ __launch_bounds__(64) void agg_kernel(
    const u16* __restrict__ X, u16* __restrict__ H,
    const int* __restrict__ offs, const int* __restrict__ nbr, int n, int d) {
    int node = blockIdx.x;
    int lane = threadIdx.x;
    float acc[FP];
    const u16* xr = X + (size_t)node * d + lane * FP;
    if (FP == 2) {
        ushort2 v = *(const ushort2*)xr;
        acc[0] = bf2f(v.x); acc[1] = bf2f(v.y);
    } else {
        ushort4 v = *(const ushort4*)xr;
        acc[0] = bf2f(v.x); acc[1] = bf2f(v.y); acc[2] = bf2f(v.z); acc[3] = bf2f(v.w);
    }
    int s = offs[node], e = offs[node + 1];
    for (int j = s; j < e; ++j) {
        int nb = nbr[j];
        const u16* nr = X + (size_t)nb * d + lane * FP;
        if (FP == 2) {
            ushort2 v = *(const ushort2*)nr;
            acc[0] += bf2f(v.x); acc[1] += bf2f(v.y);
        } else {
            ushort4 v = *(const ushort4*)nr;
            acc[0] += bf2f(v.x); acc[1] += bf2f(v.y); acc[2] += bf2f(v.z); acc[3] += bf2f(v.w);
        }
    }
    u16* hr = H + (size_t)node * d + lane * FP;
    if (FP == 2) {
        ushort2 o; o.x = f2bf(acc[0]); o.y = f2bf(acc[1]);
        *(ushort2*)hr = o;
    } else {
        ushort4 o; o.x = f2bf(acc[0]); o.y = f2bf(acc[1]); o.z = f2bf(acc[2]); o.w = f2bf(acc[3]);
        *(ushort4*)hr = o;
    }
}

// ---------------- GEMM: out = relu(A @ W + b), A bf16 [N,K], Wt bf16 [M,K] ----------------
__device__ inline f32x4 mfma16(short8 a, short8 b, f32x4 c) {
    return __builtin_amdgcn_mfma_f32_16x16x32_bf16(a, b, c, 0, 0, 0);
}

template <bool F32OUT>
__global__ __launch_bounds__(256) void gemm_kernel(
    const u16* __restrict__ A, const u16* __restrict__ Bt,
    const float* __restrict__ bias, void* __restrict__ outp,
    int Nrows, int K, int M) {
    __shared__ u16 As[64][40];  // pad 32->40: <=2-way LDS bank aliasing (free)
    __shared__ u16 Bs[64][40];
    const int c0 = blockIdx.x * 64;   // col tiles fastest -> A tile L2 reuse
    const int r0 = blockIdx.y * 64;
    const int tid = threadIdx.x;
    const int lane = tid & 63;
    const int wid = tid >> 6;
    const int wr = wid >> 1, wc = wid & 1;

    f32x4 acc[2][2];
#pragma unroll
    for (int i = 0; i < 2; i++)
#pragma unroll
        for (int j = 0; j < 2; j++) acc[i][j] = (f32x4){0.f, 0.f, 0.f, 0.f};

    const int srow = tid >> 2;        // 0..63
    const int skc = (tid & 3) << 3;   // 0,8,16,24

    for (int k0 = 0; k0 < K; k0 += 32) {
        uint4 av = make_uint4(0, 0, 0, 0);
        int gr = r0 + srow;
        if (gr < Nrows) av = *(const uint4*)(A + (size_t)gr * K + k0 + skc);
        uint4 bv = *(const uint4*)(Bt + (size_t)(c0 + srow) * K + k0 + skc);
        __syncthreads();  // protect previous iter's LDS reads
        *(uint4*)&As[srow][skc] = av;
        *(uint4*)&Bs[srow][skc] = bv;
        __syncthreads();

        const int fl = lane & 15;
        const int kg = lane >> 4;
        short8 a0 = *(const short8*)&As[wr * 32 + fl][kg * 8];
        short8 a1 = *(const short8*)&As[wr * 32 + 16 + fl][kg * 8];
        short8 b0 = *(const short8*)&Bs[wc * 32 + fl][kg * 8];
        short8 b1 = *(const short8*)&Bs[wc * 32 + 16 + fl][kg * 8];
        acc[0][0] = mfma16(a0, b0, acc[0][0]);
        acc[0][1] = mfma16(a0, b1, acc[0][1]);
        acc[1][0] = mfma16(a1, b0, acc[1][0]);
        acc[1][1] = mfma16(a1, b1, acc[1][1]);
    }

    // epilogue: C/D layout col=lane&15, row=(lane>>4)*4+j  [m89/m91 verified]
    const int col = lane & 15;
    const int rb = (lane >> 4) << 2;
#pragma unroll
    for (int fr = 0; fr < 2; fr++)
#pragma unroll
        for (int fc = 0; fc < 2; fc++) {
#pragma unroll
            for (int j = 0; j < 4; j++) {
                int r = r0 + wr * 32 + fr * 16 + rb + j;
                if (r >= Nrows) continue;
                int c = c0 + wc * 32 + fc * 16 + col;
                float v = acc[fr][fc][j] + bias[c];
                v = fmaxf(v, 0.f);
                if (F32OUT)
                    ((float*)outp)[(size_t)r * M + c] = v;
                else
                    ((u16*)outp)[(size_t)r * M + c] = f2bf(v);
            }
        }
}

// ---------------- host ----------------
extern "C" void kernel_launch(void* const* d_in, const int* in_sizes, int n_in,
                              void* d_out, int out_size, void* d_ws, size_t ws_size,
                              hipStream_t stream) {
    const int IN = 128, HID = 256, OUTD = 128;
    const int N = in_sizes[0] / IN;
    const int E = in_sizes[1] / 2;

    const float* x = (const float*)d_in[0];
    const void* edges = d_in[1];
    const float* w0a = (const float*)d_in[2];  const float* b0a = (const float*)d_in[3];
    const float* w0b = (const float*)d_in[4];  const float* b0b = (const float*)d_in[5];
    const float* w1a = (const float*)d_in[6];  const float* b1a = (const float*)d_in[7];
    const float* w1b = (const float*)d_in[8];  const float* b1b = (const float*)d_in[9];
    const float* w2a = (const float*)d_in[10]; const float* b2a = (const float*)d_in[11];
    const float* w2b = (const float*)d_in[12]; const float* b2b = (const float*)d_in[13];

    char* ws = (char*)d_ws;
    size_t off = 0;
    auto alloc = [&](size_t b) { size_t o = off; off = (off + b + 255) & ~(size_t)255; return o; };
    int* flag   = (int*)(ws + alloc(4));
    int* deg    = (int*)(ws + alloc((size_t)N * 4));
    int* incl   = (int*)(ws + alloc((size_t)N * 4));
    int* bsum   = (int*)(ws + alloc(512 * 4));
    int* boff   = (int*)(ws + alloc(512 * 4));
    int* offs   = (int*)(ws + alloc((size_t)(N + 1) * 4));
    int* cursor = (int*)(ws + alloc((size_t)N * 4));
    int* nbr    = (int*)(ws + alloc((size_t)E * 4));
    u16* wt0a = (u16*)(ws + alloc((size_t)IN * HID * 2));
    u16* wt0b = (u16*)(ws + alloc((size_t)HID * HID * 2));
    u16* wt1a = (u16*)(ws + alloc((size_t)HID * HID * 2));
    u16* wt1b = (u16*)(ws + alloc((size_t)HID * HID * 2));
    u16* wt2a = (u16*)(ws + alloc((size_t)HID * OUTD * 2));
    u16* wt2b = (u16*)(ws + alloc((size_t)OUTD * OUTD * 2));
    u16* Pa = (u16*)(ws + alloc((size_t)N * HID * 2));
    u16* Pb = (u16*)(ws + alloc((size_t)N * HID * 2));

    // CSR build
    probe_kernel<<<1, 64, 0, stream>>>(edges, N, flag);
    hipMemsetAsync(deg, 0, (size_t)N * 4, stream);
    hist_kernel<<<2048, 256, 0, stream>>>(edges, flag, E, deg);
    int nb1 = (N + 255) / 256;
    scan1_kernel<<<nb1, 256, 0, stream>>>(deg, incl, bsum, N);
    scan2_kernel<<<1, 512, 0, stream>>>(bsum, boff, nb1);
    scan3_kernel<<<nb1, 256, 0, stream>>>(incl, deg, boff, offs, cursor, N, E);
    scatter_kernel<<<2048, 256, 0, stream>>>(edges, flag, E, cursor, nbr);

    // input + weight conversion to bf16 (weights transposed: Wt[m][k])
    long long n4 = (long long)N * IN / 4;
    cvt_x_kernel<<<(int)((n4 + 255) / 256), 256, 0, stream>>>(x, Pa, n4);
    cvt_w_kernel<<<(IN * HID + 255) / 256, 256, 0, stream>>>(w0a, wt0a, IN, HID);
    cvt_w_kernel<<<(HID * HID + 255) / 256, 256, 0, stream>>>(w0b, wt0b, HID, HID);
    cvt_w_kernel<<<(HID * HID + 255) / 256, 256, 0, stream>>>(w1a, wt1a, HID, HID);
    cvt_w_kernel<<<(HID * HID + 255) / 256, 256, 0, stream>>>(w1b, wt1b, HID, HID);
    cvt_w_kernel<<<(HID * OUTD + 255) / 256, 256, 0, stream>>>(w2a, wt2a, HID, OUTD);
    cvt_w_kernel<<<(OUTD * OUTD + 255) / 256, 256, 0, stream>>>(w2b, wt2b, OUTD, OUTD);

    dim3 gH(HID / 64, (N + 63) / 64);
    dim3 gO(OUTD / 64, (N + 63) / 64);

    // layer 0: d=128 -> 256
    agg_kernel<2><<<N, 64, 0, stream>>>(Pa, Pb, offs, nbr, N, IN);
    gemm_kernel<false><<<gH, 256, 0, stream>>>(Pb, wt0a, b0a, Pa, N, IN, HID);
    gemm_kernel<false><<<gH, 256, 0, stream>>>(Pa, wt0b, b0b, Pb, N, HID, HID);
    // layer 1: 256 -> 256
    agg_kernel<4><<<N, 64, 0, stream>>>(Pb, Pa, offs, nbr, N, HID);
    gemm_kernel<false><<<gH, 256, 0, stream>>>(Pa, wt1a, b1a, Pb, N, HID, HID);
    gemm_kernel<false><<<gH, 256, 0, stream>>>(Pb, wt1b, b1b, Pa, N, HID, HID);
    // layer 2: 256 -> 128, final f32 out
    agg_kernel<4><<<N, 64, 0, stream>>>(Pa, Pb, offs, nbr, N, HID);
    gemm_kernel<false><<<gO, 256, 0, stream>>>(Pb, wt2a, b2a, Pa, N, HID, OUTD);
    gemm_kernel<true><<<gO, 256, 0, stream>>>(Pa, wt2b, b2b, d_out, N, OUTD, OUTD);
}